// Round 2
// baseline (5001.904 us; speedup 1.0000x reference)
//
#include <hip/hip_runtime.h>
#include <hip/hip_bf16.h>
#include <stdint.h>

constexpr int TK  = 4096;   // B*S tokens
constexpr int DIMC = 1024;
constexpr int DFFC = 4096;
constexpr int VOC = 32000;
constexpr int NL  = 3;

typedef __attribute__((ext_vector_type(8))) short bf16x8;
typedef __attribute__((ext_vector_type(4))) float f32x4;

__device__ __forceinline__ unsigned short f2bf(float f) {
  unsigned int u = __float_as_uint(f);
  u += 0x7FFF + ((u >> 16) & 1);           // RNE; inputs are finite
  return (unsigned short)(u >> 16);
}

__device__ __forceinline__ float gelu_f(float x) {
  float x3 = x * x * x;
  return 0.5f * x * (1.0f + tanhf(0.7978845608028654f * (x + 0.044715f * x3)));
}

// ---------------- init: gather embeddings, reset per-call state ----------------
__global__ __launch_bounds__(256) void k_init(const int* __restrict__ x,
    const float* __restrict__ emb, float* __restrict__ h,
    int* __restrict__ surv, int* __restrict__ cnts) {
  const int t = blockIdx.x, tid = threadIdx.x;
  if (t == 0 && tid < 16) cnts[tid] = (tid == 12) ? TK : 0;
  if (tid == 0) surv[t] = t;
  const int tok = x[t];
  ((float4*)(h + (size_t)t * DIMC))[tid] =
      ((const float4*)(emb + (size_t)tok * DIMC))[tid];
}

// ---------------- layernorm (two-pass, f32), compacted via surv list ----------------
__global__ __launch_bounds__(256) void k_ln(const float* __restrict__ h,
    const int* __restrict__ surv, const int* __restrict__ pM,
    const float* __restrict__ g, const float* __restrict__ b,
    float* __restrict__ hn) {
  const int bidx = blockIdx.x;
  if (bidx >= *pM) return;
  const int t = surv[bidx];
  const int tid = threadIdx.x;
  const int lane = tid & 63, wid = tid >> 6;
  __shared__ float sm[4];
  float4 v = ((const float4*)(h + (size_t)t * DIMC))[tid];
  float s = v.x + v.y + v.z + v.w;
#pragma unroll
  for (int o = 32; o; o >>= 1) s += __shfl_down(s, o);
  if (lane == 0) sm[wid] = s;
  __syncthreads();
  const float mean = (sm[0] + sm[1] + sm[2] + sm[3]) * (1.0f / DIMC);
  __syncthreads();
  float4 d;
  d.x = v.x - mean; d.y = v.y - mean; d.z = v.z - mean; d.w = v.w - mean;
  float q = d.x * d.x + d.y * d.y + d.z * d.z + d.w * d.w;
#pragma unroll
  for (int o = 32; o; o >>= 1) q += __shfl_down(q, o);
  if (lane == 0) sm[wid] = q;
  __syncthreads();
  const float var = (sm[0] + sm[1] + sm[2] + sm[3]) * (1.0f / DIMC);
  const float rstd = 1.0f / sqrtf(var + 1e-5f);
  float4 gg = ((const float4*)g)[tid];
  float4 bb = ((const float4*)b)[tid];
  float4 o4;
  o4.x = d.x * rstd * gg.x + bb.x;
  o4.y = d.y * rstd * gg.y + bb.y;
  o4.z = d.z * rstd * gg.z + bb.z;
  o4.w = d.w * rstd * gg.w + bb.w;
  ((float4*)(hn + (size_t)bidx * DIMC))[tid] = o4;
}

// ---------------- f32 tiled GEMM, conflict-free LDS, BK=16 ----------------
// EPI==0: C = gelu(A@B + bias)   (gemm1)
// EPI==1: C = A@B partial slab   (gemm2 split-K; z = blockIdx.z selects K-slice
//          and output slab C + z*TK*ldc; bias/resid applied later in k_decide)
template<int EPI>
__global__ __launch_bounds__(256) void k_gemm(
    const float* __restrict__ A, int lda,
    const float* __restrict__ B, int ldb,
    const float* __restrict__ bias,
    float* __restrict__ C, int ldc,
    const int* __restrict__ pM, int Kpart)
{
  constexpr int BM = 128, BN = 128, BK = 16;
  const int M = *pM;
  const int rb = blockIdx.x;
  if (rb * BM >= M) return;
  const int n0 = blockIdx.y * BN;
  const int z  = blockIdx.z;
  A += (size_t)z * Kpart;
  B += (size_t)z * Kpart * ldb;
  C += (size_t)z * TK * ldc;

  __shared__ __align__(16) float As[2][BK][BM];
  __shared__ __align__(16) float Bs[2][BK][BN];
  const int tid = threadIdx.x;
  // staging indices
  const int ar = tid >> 2, ac = (tid & 3) * 4;        // A rows ar, ar+64; k-cols ac..ac+3
  const int br = (tid >> 5) * 2, bc = (tid & 31) * 4; // B rows br, br+1; n-cols bc..bc+3
  const float* Ag = A + (size_t)(rb * BM + ar) * lda + ac;
  const float* Bg = B + (size_t)br * ldb + n0 + bc;

  float4 va0, va1, vb0, vb1;
  auto gload = [&](int kt) {
    const float* ap = Ag + kt * BK;
    va0 = *(const float4*)ap;
    va1 = *(const float4*)(ap + (size_t)64 * lda);
    const float* bp = Bg + (size_t)kt * BK * ldb;
    vb0 = *(const float4*)bp;
    vb1 = *(const float4*)(bp + ldb);
  };
  auto swr = [&](int buf) {
    As[buf][ac + 0][ar] = va0.x; As[buf][ac + 1][ar] = va0.y;
    As[buf][ac + 2][ar] = va0.z; As[buf][ac + 3][ar] = va0.w;
    As[buf][ac + 0][ar + 64] = va1.x; As[buf][ac + 1][ar + 64] = va1.y;
    As[buf][ac + 2][ar + 64] = va1.z; As[buf][ac + 3][ar + 64] = va1.w;
    *(float4*)&Bs[buf][br][bc]     = vb0;
    *(float4*)&Bs[buf][br + 1][bc] = vb1;
  };

  float acc[2][2][4][4] = {};
  gload(0); swr(0); __syncthreads();
  const int NT = Kpart / BK;
  const int tm4 = (tid >> 4) * 4, tn4 = (tid & 15) * 4;  // micro-tile: rows tm4(+64), cols tn4(+64)
  for (int kt = 0; kt < NT; ++kt) {
    const int buf = kt & 1;
    if (kt + 1 < NT) gload(kt + 1);
#pragma unroll
    for (int k = 0; k < BK; ++k) {
      float4 a0 = *(float4*)&As[buf][k][tm4];
      float4 a1 = *(float4*)&As[buf][k][tm4 + 64];
      float4 b0 = *(float4*)&Bs[buf][k][tn4];
      float4 b1 = *(float4*)&Bs[buf][k][tn4 + 64];
      const float aa[8] = {a0.x, a0.y, a0.z, a0.w, a1.x, a1.y, a1.z, a1.w};
      const float bb[8] = {b0.x, b0.y, b0.z, b0.w, b1.x, b1.y, b1.z, b1.w};
#pragma unroll
      for (int i = 0; i < 8; ++i)
#pragma unroll
        for (int j = 0; j < 8; ++j)
          acc[i >> 2][j >> 2][i & 3][j & 3] += aa[i] * bb[j];
    }
    if (kt + 1 < NT) { swr(buf ^ 1); __syncthreads(); }
  }

#pragma unroll
  for (int ib = 0; ib < 2; ++ib)
#pragma unroll
    for (int i = 0; i < 4; ++i) {
      const int m = rb * BM + ib * 64 + tm4 + i;
      float* crow = C + (size_t)m * ldc + n0;
#pragma unroll
      for (int jb = 0; jb < 2; ++jb) {
        float4 o;
        o.x = acc[ib][jb][i][0]; o.y = acc[ib][jb][i][1];
        o.z = acc[ib][jb][i][2]; o.w = acc[ib][jb][i][3];
        if constexpr (EPI == 0) {
          float4 bf = *(const float4*)(bias + n0 + jb * 64 + tn4);
          o.x = gelu_f(o.x + bf.x); o.y = gelu_f(o.y + bf.y);
          o.z = gelu_f(o.z + bf.z); o.w = gelu_f(o.w + bf.w);
        }
        *(float4*)(crow + jb * 64 + tn4) = o;
      }
    }
}

// ---------------- decide: o = h + p0 + p1 + b2; cos; route token ----------------
__global__ __launch_bounds__(256) void k_decide(
    float* __restrict__ h, const float* __restrict__ p,
    const float* __restrict__ bias,
    const int* __restrict__ surv_in, int* __restrict__ surv_out,
    const int* __restrict__ pM, int* __restrict__ cnts,
    int* __restrict__ exit_idx, unsigned short* __restrict__ hexit,
    int stage)
{
  const int bidx = blockIdx.x;
  if (bidx >= *pM) return;
  const int t = surv_in[bidx];
  const int tid = threadIdx.x;
  const int lane = tid & 63, wid = tid >> 6;
  __shared__ float sm[12];
  __shared__ int sif[2];
  float4 a  = ((const float4*)(h + (size_t)t * DIMC))[tid];
  float4 p0 = ((const float4*)(p + (size_t)bidx * DIMC))[tid];
  float4 p1 = ((const float4*)(p + (size_t)(TK + bidx) * DIMC))[tid];
  float4 bb = ((const float4*)bias)[tid];
  float4 o;
  o.x = a.x + p0.x + p1.x + bb.x;
  o.y = a.y + p0.y + p1.y + bb.y;
  o.z = a.z + p0.z + p1.z + bb.z;
  o.w = a.w + p0.w + p1.w + bb.w;
  float hh = a.x * a.x + a.y * a.y + a.z * a.z + a.w * a.w;
  float ho = a.x * o.x + a.y * o.y + a.z * o.z + a.w * o.w;
  float oo = o.x * o.x + o.y * o.y + o.z * o.z + o.w * o.w;
#pragma unroll
  for (int off = 32; off; off >>= 1) {
    hh += __shfl_down(hh, off);
    ho += __shfl_down(ho, off);
    oo += __shfl_down(oo, off);
  }
  if (lane == 0) { sm[wid] = hh; sm[4 + wid] = ho; sm[8 + wid] = oo; }
  __syncthreads();
  if (tid == 0) {
    int take;
    if (stage == NL - 1) take = 1;
    else {
      const float HH = sm[0] + sm[1] + sm[2] + sm[3];
      const float HO = sm[4] + sm[5] + sm[6] + sm[7];
      const float OO = sm[8] + sm[9] + sm[10] + sm[11];
      const float cosv = HO / (sqrtf(HH) * sqrtf(OO) + 1e-8f);
      take = (cosv >= 0.98f) ? 1 : 0;
    }
    int pos;
    if (take) {
      pos = atomicAdd(&cnts[stage], 1);
      exit_idx[pos] = t;
    } else {
      pos = atomicAdd(&cnts[4 + stage], 1);
      surv_out[pos] = t;
    }
    sif[0] = take; sif[1] = pos;
  }
  __syncthreads();
  if (sif[0]) {
    unsigned short* dst = hexit + (size_t)sif[1] * DIMC;
    ushort4 u;
    u.x = f2bf(o.x); u.y = f2bf(o.y); u.z = f2bf(o.z); u.w = f2bf(o.w);
    ((ushort4*)dst)[tid] = u;
  } else {
    ((float4*)(h + (size_t)t * DIMC))[tid] = o;
  }
}

// ---------------- logits: compacted bf16 MFMA GEMM, scatter-store rows ----------------
__global__ __launch_bounds__(256) void k_logits(
    const unsigned short* __restrict__ Ab,   // hexit bits [TK][DIMC]
    const float* __restrict__ Wout,          // [VOC][DIMC] f32
    const int* __restrict__ exit_idx,
    const int* __restrict__ pcnt,
    float* __restrict__ out)
{
  constexpr int BK = 32;
  const int cnt = *pcnt;
  const int rb = blockIdx.x, cb = blockIdx.y;
  if (rb * 128 >= cnt) return;
  __shared__ __align__(16) unsigned short As[2][128][40];
  __shared__ __align__(16) unsigned short Bs[2][128][40];
  const int tid = threadIdx.x;
  const int lane = tid & 63, wid = tid >> 6;
  const int wr = wid >> 1, wc = wid & 1;
  const int lr = lane & 15, lk = (lane >> 4) * 8;

  const int a_r = tid >> 2, a_c = (tid & 3) * 8;
  const int b_r = tid >> 3, b_c = (tid & 7) * 4;
  const unsigned short* Agp = Ab + (size_t)(rb * 128) * DIMC;
  const float* Bgp = Wout + (size_t)(cb * 128) * DIMC;

  f32x4 acc[4][4];
#pragma unroll
  for (int mi = 0; mi < 4; ++mi)
#pragma unroll
    for (int ni = 0; ni < 4; ++ni)
      acc[mi][ni] = (f32x4){0.f, 0.f, 0.f, 0.f};

  int4 va0, va1; float4 vb[4];
  auto loadAB = [&](int kt) {
    va0 = *(const int4*)(Agp + (size_t)a_r * DIMC + kt * BK + a_c);
    va1 = *(const int4*)(Agp + (size_t)(a_r + 64) * DIMC + kt * BK + a_c);
#pragma unroll
    for (int q = 0; q < 4; ++q)
      vb[q] = *(const float4*)(Bgp + (size_t)(b_r + 32 * q) * DIMC + kt * BK + b_c);
  };
  auto writeAB = [&](int buf) {
    *(int4*)&As[buf][a_r][a_c] = va0;
    *(int4*)&As[buf][a_r + 64][a_c] = va1;
#pragma unroll
    for (int q = 0; q < 4; ++q) {
      ushort4 u;
      u.x = f2bf(vb[q].x); u.y = f2bf(vb[q].y);
      u.z = f2bf(vb[q].z); u.w = f2bf(vb[q].w);
      *(ushort4*)&Bs[buf][b_r + 32 * q][b_c] = u;
    }
  };

  loadAB(0);
  writeAB(0);
  __syncthreads();
  const int NT = DIMC / BK;   // 32
  for (int kt = 0; kt < NT; ++kt) {
    const int buf = kt & 1;
    if (kt + 1 < NT) loadAB(kt + 1);
    bf16x8 aF[4], bF[4];
#pragma unroll
    for (int mi = 0; mi < 4; ++mi)
      aF[mi] = *(const bf16x8*)&As[buf][wr * 64 + mi * 16 + lr][lk];
#pragma unroll
    for (int ni = 0; ni < 4; ++ni)
      bF[ni] = *(const bf16x8*)&Bs[buf][wc * 64 + ni * 16 + lr][lk];
#pragma unroll
    for (int mi = 0; mi < 4; ++mi)
#pragma unroll
      for (int ni = 0; ni < 4; ++ni)
        acc[mi][ni] = __builtin_amdgcn_mfma_f32_16x16x32_bf16(aF[mi], bF[ni], acc[mi][ni], 0, 0, 0);
    if (kt + 1 < NT) {
      writeAB(buf ^ 1);
      __syncthreads();
    }
  }

  const int mvalid = cnt - rb * 128;
  const int rbase = (lane >> 4) * 4;
#pragma unroll
  for (int mi = 0; mi < 4; ++mi) {
#pragma unroll
    for (int r = 0; r < 4; ++r) {
      const int mrow = wr * 64 + mi * 16 + rbase + r;
      if (mrow < mvalid) {
        const int tok = exit_idx[rb * 128 + mrow];
        float* orow = out + (size_t)tok * VOC + cb * 128 + wc * 64 + lr;
#pragma unroll
        for (int ni = 0; ni < 4; ++ni)
          orow[ni * 16] = acc[mi][ni][r];
      }
    }
  }
}

// ---------------- host ----------------
extern "C" void kernel_launch(void* const* d_in, const int* in_sizes, int n_in,
                              void* d_out, int out_size, void* d_ws, size_t ws_size,
                              hipStream_t stream)
{
  const int*   x    = (const int*)d_in[0];
  const float* emb  = (const float*)d_in[1];
  const float* ln_g = (const float*)d_in[2];
  const float* ln_b = (const float*)d_in[3];
  const float* W1   = (const float*)d_in[4];
  const float* b1   = (const float*)d_in[5];
  const float* W2   = (const float*)d_in[6];
  const float* b2   = (const float*)d_in[7];
  const float* Wout = (const float*)d_in[8];
  float* out = (float*)d_out;

  char* p = (char*)d_ws;
  size_t off = 0;
  auto alloc = [&](size_t bytes) -> void* {
    void* r = p + off;
    off += (bytes + 255) & ~(size_t)255;
    return r;
  };
  float* h    = (float*)alloc((size_t)TK * DIMC * 4);
  float* pbuf = (float*)alloc((size_t)2 * TK * DIMC * 4);  // split-K partials; part0 doubles as hn
  float* hn   = pbuf;
  float* act  = (float*)alloc((size_t)TK * DFFC * 4);
  unsigned short* hexit = (unsigned short*)alloc((size_t)TK * DIMC * 2);
  int* exit_idx = (int*)alloc((size_t)TK * 4);
  int* surv_a   = (int*)alloc((size_t)TK * 4);
  int* surv_b   = (int*)alloc((size_t)TK * 4);
  int* cnts     = (int*)alloc(64 * 4);
  // cnts[0..2]=exit counts; cnts[4..6]=survivor counts; cnts[12]=TK

  k_init<<<TK, 256, 0, stream>>>(x, emb, h, surv_a, cnts);
  int* surv_in  = surv_a;
  int* surv_out = surv_b;
  for (int i = 0; i < NL; ++i) {
    const int* pM = (i == 0) ? (cnts + 12) : (cnts + 4 + (i - 1));
    k_ln<<<TK, 256, 0, stream>>>(h, surv_in, pM, ln_g + i * DIMC, ln_b + i * DIMC, hn);
    k_gemm<0><<<dim3(TK / 128, DFFC / 128, 1), 256, 0, stream>>>(
        hn, DIMC, W1 + (size_t)i * DIMC * DFFC, DFFC, b1 + (size_t)i * DFFC,
        act, DFFC, pM, DIMC);
    k_gemm<1><<<dim3(TK / 128, DIMC / 128, 2), 256, 0, stream>>>(
        act, DFFC, W2 + (size_t)i * DFFC * DIMC, DIMC, nullptr,
        pbuf, DIMC, pM, DFFC / 2);
    k_decide<<<TK, 256, 0, stream>>>(h, pbuf, b2 + (size_t)i * DIMC,
        surv_in, surv_out, pM, cnts, exit_idx, hexit, i);
    k_logits<<<dim3(TK / 128, VOC / 128), 256, 0, stream>>>(
        hexit, Wout, exit_idx, cnts + i, out);
    int* tmp = surv_in; surv_in = surv_out; surv_out = tmp;
  }
}

// Round 3
// 1669.916 us; speedup vs baseline: 2.9953x; 2.9953x over previous
//
#include <hip/hip_runtime.h>
#include <hip/hip_bf16.h>
#include <stdint.h>

constexpr int TK   = 4096;   // B*S tokens
constexpr int DIMC = 1024;
constexpr int DFFC = 4096;
constexpr int VOC  = 32000;
constexpr int NL   = 3;

typedef __attribute__((ext_vector_type(8))) short bf16x8;
typedef __attribute__((ext_vector_type(8))) _Float16 half8;
typedef __attribute__((ext_vector_type(4))) float f32x4;
using u16 = unsigned short;

__device__ __forceinline__ u16 f2bf(float f) {
  unsigned int u = __float_as_uint(f);
  u += 0x7FFF + ((u >> 16) & 1);           // RNE; inputs finite
  return (u16)(u >> 16);
}

__device__ __forceinline__ void split16(float v, u16& hi, u16& lo) {
  _Float16 a = (_Float16)v;
  _Float16 b = (_Float16)(v - (float)a);
  hi = __builtin_bit_cast(u16, a);
  lo = __builtin_bit_cast(u16, b);
}

__device__ __forceinline__ float gelu_f(float x) {
  float x3 = x * x * x;
  return 0.5f * x * (1.0f + tanhf(0.7978845608028654f * (x + 0.044715f * x3)));
}

// async global->LDS, 16B per lane; LDS dest = uniform base + lane*16
__device__ __forceinline__ void gll16(const void* g, void* l) {
  __builtin_amdgcn_global_load_lds(
      (const __attribute__((address_space(1))) unsigned int*)g,
      (__attribute__((address_space(3))) unsigned int*)l, 16, 0, 0);
}

// ---------------- init ----------------
__global__ __launch_bounds__(256) void k_init(const int* __restrict__ x,
    const float* __restrict__ emb, float* __restrict__ h,
    int* __restrict__ surv, int* __restrict__ cnts) {
  const int t = blockIdx.x, tid = threadIdx.x;
  if (t == 0 && tid < 16) cnts[tid] = (tid == 12) ? TK : 0;
  if (tid == 0) surv[t] = t;
  const int tok = x[t];
  ((float4*)(h + (size_t)t * DIMC))[tid] =
      ((const float4*)(emb + (size_t)tok * DIMC))[tid];
}

// ---------------- layernorm -> 2 fp16 planes (x16 scale) ----------------
__global__ __launch_bounds__(256) void k_ln(const float* __restrict__ h,
    const int* __restrict__ surv, const int* __restrict__ pM,
    const float* __restrict__ g, const float* __restrict__ b,
    u16* __restrict__ hn1, u16* __restrict__ hn2) {
  const int bidx = blockIdx.x;
  if (bidx >= *pM) return;
  const int t = surv[bidx];
  const int tid = threadIdx.x;
  const int lane = tid & 63, wid = tid >> 6;
  __shared__ float sm[4];
  float4 v = ((const float4*)(h + (size_t)t * DIMC))[tid];
  float s = v.x + v.y + v.z + v.w;
#pragma unroll
  for (int o = 32; o; o >>= 1) s += __shfl_down(s, o);
  if (lane == 0) sm[wid] = s;
  __syncthreads();
  const float mean = (sm[0] + sm[1] + sm[2] + sm[3]) * (1.0f / DIMC);
  __syncthreads();
  float4 d;
  d.x = v.x - mean; d.y = v.y - mean; d.z = v.z - mean; d.w = v.w - mean;
  float q = d.x * d.x + d.y * d.y + d.z * d.z + d.w * d.w;
#pragma unroll
  for (int o = 32; o; o >>= 1) q += __shfl_down(q, o);
  if (lane == 0) sm[wid] = q;
  __syncthreads();
  const float var = (sm[0] + sm[1] + sm[2] + sm[3]) * (1.0f / DIMC);
  const float rstd = 1.0f / sqrtf(var + 1e-5f);
  float4 gg = ((const float4*)g)[tid];
  float4 bb = ((const float4*)b)[tid];
  float o4[4];
  o4[0] = (d.x * rstd * gg.x + bb.x) * 16.f;
  o4[1] = (d.y * rstd * gg.y + bb.y) * 16.f;
  o4[2] = (d.z * rstd * gg.z + bb.z) * 16.f;
  o4[3] = (d.w * rstd * gg.w + bb.w) * 16.f;
  ushort4 u1, u2;
  split16(o4[0], u1.x, u2.x); split16(o4[1], u1.y, u2.y);
  split16(o4[2], u1.z, u2.z); split16(o4[3], u1.w, u2.w);
  ((ushort4*)(hn1 + (size_t)bidx * DIMC))[tid] = u1;
  ((ushort4*)(hn2 + (size_t)bidx * DIMC))[tid] = u2;
}

// ---------------- weight transpose + fp16 2-split (x256 scale) ----------------
// in W[K][N] f32  ->  O1,O2 [N][K] fp16
__global__ __launch_bounds__(256) void k_splitw(const float* __restrict__ W,
    int K, int N, u16* __restrict__ O1, u16* __restrict__ O2) {
  __shared__ float t[32][33];
  const int bk = blockIdx.x * 32, bn = blockIdx.y * 32;
  const int lx = threadIdx.x & 31, ly = threadIdx.x >> 5;
#pragma unroll
  for (int i = 0; i < 32; i += 8)
    t[ly + i][lx] = W[(size_t)(bk + ly + i) * N + bn + lx];
  __syncthreads();
#pragma unroll
  for (int i = 0; i < 32; i += 8) {
    float v = t[lx][ly + i] * 256.f;
    u16 h1, h2; split16(v, h1, h2);
    const size_t o = (size_t)(bn + ly + i) * K + bk + lx;
    O1[o] = h1; O2[o] = h2;
  }
}

// ---------------- f32 -> bf16 bulk convert (Wout) ----------------
__global__ __launch_bounds__(256) void k_cvtb(const float* __restrict__ in,
    u16* __restrict__ o, int n4) {
  int i = blockIdx.x * blockDim.x + threadIdx.x;
  const int stride = gridDim.x * blockDim.x;
  for (; i < n4; i += stride) {
    float4 v = ((const float4*)in)[i];
    ushort4 u;
    u.x = f2bf(v.x); u.y = f2bf(v.y); u.z = f2bf(v.z); u.w = f2bf(v.w);
    ((ushort4*)o)[i] = u;
  }
}

// ---------------- fp16-2-split MFMA GEMM: C = (A1+A2)(B1+B2)^T ----------------
// A planes [Mcap][ldk], B planes [N][ldk], all k-contiguous.
// EPI==0: act = split64(gelu(C*oscale + bias))  -> O1,O2 [TK][N]
// EPI==1: PO[z*TK + m][n] = C*oscale            (split-K partials)
template<int EPI>
__global__ __launch_bounds__(512, 4) void k_mlp(
    const u16* __restrict__ A1, const u16* __restrict__ A2,
    const u16* __restrict__ B1, const u16* __restrict__ B2,
    const int* __restrict__ pM, int ldk, int Kpart,
    const float* __restrict__ bias,
    u16* __restrict__ O1, u16* __restrict__ O2,
    float* __restrict__ PO, int N, float oscale)
{
  const int M = *pM;
  const int rb = blockIdx.x;
  if (rb * 128 >= M) return;
  const int n0 = blockIdx.y * 128;
  const int z  = blockIdx.z;
  const int kz = z * Kpart;

  __shared__ u16 S[4][128 * 64];   // A1,A2,B1,B2 tiles; 64 KiB total
  const int tid = threadIdx.x;
  const int w = tid >> 6, l = tid & 63;

  // ---- staging constants (both-sides swizzle: linear LDS dest, XOR'd source)
  const int sr = l >> 3;                       // row within 8-row chunk
  const int sc = ((l & 7) ^ sr) * 8;           // swizzled source k-chunk (elems)
  const u16* gsrc[4] = {A1, A2, B1, B2};
  const u16* gp[4][2];
  void* lp[4][2];
#pragma unroll
  for (int p = 0; p < 4; ++p) {
    const int row0 = (p < 2) ? rb * 128 : n0;
#pragma unroll
    for (int j = 0; j < 2; ++j) {
      const int r = w * 16 + j * 8 + sr;
      gp[p][j] = gsrc[p] + (size_t)(row0 + r) * ldk + kz + sc;
      lp[p][j] = (void*)&S[p][(w * 16 + j * 8) * 64];
    }
  }

  // ---- compute constants
  const int wr = w >> 2, wc = w & 3;           // 2x4 wave grid, wave tile 64x32
  const int lr = l & 15, hi = l >> 4;
  const int sw = lr & 7;
  const int swz0 = ((hi) ^ sw) * 8;            // ks=0 chunk byte-swizzle (elems)
  const int swz1 = ((4 + hi) ^ sw) * 8;        // ks=1
  const int abase = (wr * 64 + lr) * 64;
  const int bbase = (wc * 32 + lr) * 64;

  f32x4 acc[4][2];
#pragma unroll
  for (int mi = 0; mi < 4; ++mi)
#pragma unroll
    for (int ni = 0; ni < 2; ++ni) acc[mi][ni] = (f32x4){0.f, 0.f, 0.f, 0.f};

  const int NT = Kpart / 64;
  for (int kt = 0; kt < NT; ++kt) {
    __syncthreads();               // prior reads of S complete
#pragma unroll
    for (int p = 0; p < 4; ++p)
#pragma unroll
      for (int j = 0; j < 2; ++j)
        gll16(gp[p][j] + kt * 64, lp[p][j]);
    __syncthreads();               // compiler drains vmcnt(0) before barrier
#pragma unroll
    for (int ks = 0; ks < 2; ++ks) {
      const int kswz = ks ? swz1 : swz0;
      half8 a1[4], a2[4], b1v[2], b2v[2];
#pragma unroll
      for (int mi = 0; mi < 4; ++mi) {
        a1[mi] = *(const half8*)&S[0][abase + mi * 1024 + kswz];
        a2[mi] = *(const half8*)&S[1][abase + mi * 1024 + kswz];
      }
#pragma unroll
      for (int ni = 0; ni < 2; ++ni) {
        b1v[ni] = *(const half8*)&S[2][bbase + ni * 1024 + kswz];
        b2v[ni] = *(const half8*)&S[3][bbase + ni * 1024 + kswz];
      }
#pragma unroll
      for (int mi = 0; mi < 4; ++mi)
#pragma unroll
        for (int ni = 0; ni < 2; ++ni) {
          acc[mi][ni] = __builtin_amdgcn_mfma_f32_16x16x32_f16(a2[mi], b2v[ni], acc[mi][ni], 0, 0, 0);
          acc[mi][ni] = __builtin_amdgcn_mfma_f32_16x16x32_f16(a2[mi], b1v[ni], acc[mi][ni], 0, 0, 0);
          acc[mi][ni] = __builtin_amdgcn_mfma_f32_16x16x32_f16(a1[mi], b2v[ni], acc[mi][ni], 0, 0, 0);
          acc[mi][ni] = __builtin_amdgcn_mfma_f32_16x16x32_f16(a1[mi], b1v[ni], acc[mi][ni], 0, 0, 0);
        }
    }
  }

#pragma unroll
  for (int mi = 0; mi < 4; ++mi)
#pragma unroll
    for (int ni = 0; ni < 2; ++ni) {
      const int n = n0 + wc * 32 + ni * 16 + lr;
#pragma unroll
      for (int r = 0; r < 4; ++r) {
        const int m = rb * 128 + wr * 64 + mi * 16 + hi * 4 + r;
        float v = acc[mi][ni][r] * oscale;
        if constexpr (EPI == 0) {
          v = gelu_f(v + bias[n]) * 64.f;
          u16 h1, h2; split16(v, h1, h2);
          O1[(size_t)m * N + n] = h1;
          O2[(size_t)m * N + n] = h2;
        } else {
          PO[(size_t)(z * TK + m) * N + n] = v;
        }
      }
    }
}

// ---------------- decide: o = h + p0 + p1 + b2; cos; route token ----------------
__global__ __launch_bounds__(256) void k_decide(
    float* __restrict__ h, const float* __restrict__ p,
    const float* __restrict__ bias,
    const int* __restrict__ surv_in, int* __restrict__ surv_out,
    const int* __restrict__ pM, int* __restrict__ cnts,
    int* __restrict__ exit_idx, u16* __restrict__ hexit,
    int stage)
{
  const int bidx = blockIdx.x;
  if (bidx >= *pM) return;
  const int t = surv_in[bidx];
  const int tid = threadIdx.x;
  const int lane = tid & 63, wid = tid >> 6;
  __shared__ float sm[12];
  __shared__ int sif[2];
  float4 a  = ((const float4*)(h + (size_t)t * DIMC))[tid];
  float4 p0 = ((const float4*)(p + (size_t)bidx * DIMC))[tid];
  float4 p1 = ((const float4*)(p + (size_t)(TK + bidx) * DIMC))[tid];
  float4 bb = ((const float4*)bias)[tid];
  float4 o;
  o.x = a.x + p0.x + p1.x + bb.x;
  o.y = a.y + p0.y + p1.y + bb.y;
  o.z = a.z + p0.z + p1.z + bb.z;
  o.w = a.w + p0.w + p1.w + bb.w;
  float hh = a.x * a.x + a.y * a.y + a.z * a.z + a.w * a.w;
  float ho = a.x * o.x + a.y * o.y + a.z * o.z + a.w * o.w;
  float oo = o.x * o.x + o.y * o.y + o.z * o.z + o.w * o.w;
#pragma unroll
  for (int off = 32; off; off >>= 1) {
    hh += __shfl_down(hh, off);
    ho += __shfl_down(ho, off);
    oo += __shfl_down(oo, off);
  }
  if (lane == 0) { sm[wid] = hh; sm[4 + wid] = ho; sm[8 + wid] = oo; }
  __syncthreads();
  if (tid == 0) {
    int take;
    if (stage == NL - 1) take = 1;
    else {
      const float HH = sm[0] + sm[1] + sm[2] + sm[3];
      const float HO = sm[4] + sm[5] + sm[6] + sm[7];
      const float OO = sm[8] + sm[9] + sm[10] + sm[11];
      const float cosv = HO / (sqrtf(HH) * sqrtf(OO) + 1e-8f);
      take = (cosv >= 0.98f) ? 1 : 0;
    }
    int pos;
    if (take) {
      pos = atomicAdd(&cnts[stage], 1);
      exit_idx[pos] = t;
    } else {
      pos = atomicAdd(&cnts[4 + stage], 1);
      surv_out[pos] = t;
    }
    sif[0] = take; sif[1] = pos;
  }
  __syncthreads();
  if (sif[0]) {
    u16* dst = hexit + (size_t)sif[1] * DIMC;
    ushort4 u;
    u.x = f2bf(o.x); u.y = f2bf(o.y); u.z = f2bf(o.z); u.w = f2bf(o.w);
    ((ushort4*)dst)[tid] = u;
  } else {
    ((float4*)(h + (size_t)t * DIMC))[tid] = o;
  }
}

// ---------------- logits: bf16 MFMA GEMM (same engine, 1 plane each) ----------------
__global__ __launch_bounds__(512, 4) void k_logits(
    const u16* __restrict__ Ab,        // hexit [TK][DIMC] bf16
    const u16* __restrict__ Wb,        // Woutb [VOC][DIMC] bf16
    const int* __restrict__ exit_idx,
    const int* __restrict__ pcnt,
    float* __restrict__ out)
{
  const int cnt = *pcnt;
  const int rb = blockIdx.x;
  if (rb * 128 >= cnt) return;
  const int cb = blockIdx.y;

  __shared__ u16 S[2][128 * 64];       // 32 KiB
  const int tid = threadIdx.x;
  const int w = tid >> 6, l = tid & 63;

  const int sr = l >> 3;
  const int sc = ((l & 7) ^ sr) * 8;
  const u16* gp[2][2];
  void* lp[2][2];
#pragma unroll
  for (int p = 0; p < 2; ++p) {
    const u16* src = p ? Wb : Ab;
    const int row0 = p ? cb * 128 : rb * 128;
#pragma unroll
    for (int j = 0; j < 2; ++j) {
      const int r = w * 16 + j * 8 + sr;
      gp[p][j] = src + (size_t)(row0 + r) * DIMC + sc;
      lp[p][j] = (void*)&S[p][(w * 16 + j * 8) * 64];
    }
  }

  const int wr = w >> 2, wc = w & 3;
  const int lr = l & 15, hi = l >> 4;
  const int sw = lr & 7;
  const int swz0 = ((hi) ^ sw) * 8;
  const int swz1 = ((4 + hi) ^ sw) * 8;
  const int abase = (wr * 64 + lr) * 64;
  const int bbase = (wc * 32 + lr) * 64;

  f32x4 acc[4][2];
#pragma unroll
  for (int mi = 0; mi < 4; ++mi)
#pragma unroll
    for (int ni = 0; ni < 2; ++ni) acc[mi][ni] = (f32x4){0.f, 0.f, 0.f, 0.f};

  const int NT = DIMC / 64;            // 16
  for (int kt = 0; kt < NT; ++kt) {
    __syncthreads();
#pragma unroll
    for (int p = 0; p < 2; ++p)
#pragma unroll
      for (int j = 0; j < 2; ++j)
        gll16(gp[p][j] + kt * 64, lp[p][j]);
    __syncthreads();
#pragma unroll
    for (int ks = 0; ks < 2; ++ks) {
      const int kswz = ks ? swz1 : swz0;
      bf16x8 aF[4], bF[2];
#pragma unroll
      for (int mi = 0; mi < 4; ++mi)
        aF[mi] = *(const bf16x8*)&S[0][abase + mi * 1024 + kswz];
#pragma unroll
      for (int ni = 0; ni < 2; ++ni)
        bF[ni] = *(const bf16x8*)&S[1][bbase + ni * 1024 + kswz];
#pragma unroll
      for (int mi = 0; mi < 4; ++mi)
#pragma unroll
        for (int ni = 0; ni < 2; ++ni)
          acc[mi][ni] = __builtin_amdgcn_mfma_f32_16x16x32_bf16(aF[mi], bF[ni], acc[mi][ni], 0, 0, 0);
    }
  }

  const int mvalid = cnt - rb * 128;
#pragma unroll
  for (int mi = 0; mi < 4; ++mi)
#pragma unroll
    for (int r = 0; r < 4; ++r) {
      const int mrow = wr * 64 + mi * 16 + hi * 4 + r;
      if (mrow < mvalid) {
        const int tok = exit_idx[rb * 128 + mrow];
        float* orow = out + (size_t)tok * VOC + cb * 128 + wc * 32 + lr;
#pragma unroll
        for (int ni = 0; ni < 2; ++ni)
          orow[ni * 16] = acc[mi][ni][r];
      }
    }
}

// ---------------- host ----------------
extern "C" void kernel_launch(void* const* d_in, const int* in_sizes, int n_in,
                              void* d_out, int out_size, void* d_ws, size_t ws_size,
                              hipStream_t stream)
{
  const int*   x    = (const int*)d_in[0];
  const float* emb  = (const float*)d_in[1];
  const float* ln_g = (const float*)d_in[2];
  const float* ln_b = (const float*)d_in[3];
  const float* W1   = (const float*)d_in[4];
  const float* b1   = (const float*)d_in[5];
  const float* W2   = (const float*)d_in[6];
  const float* b2   = (const float*)d_in[7];
  const float* Wout = (const float*)d_in[8];
  float* out = (float*)d_out;

  char* p = (char*)d_ws;
  size_t off = 0;
  auto alloc = [&](size_t bytes) -> void* {
    void* r = p + off;
    off += (bytes + 255) & ~(size_t)255;
    return r;
  };
  float* h    = (float*)alloc((size_t)TK * DIMC * 4);
  float* pbuf = (float*)alloc((size_t)2 * TK * DIMC * 4);   // gemm2 partials; hn planes alias
  u16* hn1 = (u16*)pbuf;
  u16* hn2 = hn1 + (size_t)TK * DIMC;
  u16* act1 = (u16*)alloc((size_t)TK * DFFC * 2);           // contiguous with act2
  u16* act2 = (u16*)alloc((size_t)TK * DFFC * 2);
  u16* Woutb = act1;                                        // reuses act region (dead at logits time)
  u16* W1t = (u16*)alloc((size_t)2 * DFFC * DIMC * 2);
  u16* W2t = (u16*)alloc((size_t)2 * DIMC * DFFC * 2);
  u16* hexit = (u16*)alloc((size_t)TK * DIMC * 2);
  int* exit_idx = (int*)alloc((size_t)TK * 4);
  int* surv_a   = (int*)alloc((size_t)TK * 4);
  int* surv_b   = (int*)alloc((size_t)TK * 4);
  int* cnts     = (int*)alloc(64 * 4);
  // cnts[0..2]=exit counts; cnts[4..6]=survivor counts; cnts[12]=TK

  k_init<<<TK, 256, 0, stream>>>(x, emb, h, surv_a, cnts);
  int* surv_in  = surv_a;
  int* surv_out = surv_b;
  for (int i = 0; i < NL; ++i) {
    const int* pM = (i == 0) ? (cnts + 12) : (cnts + 4 + (i - 1));
    k_ln<<<TK, 256, 0, stream>>>(h, surv_in, pM, ln_g + i * DIMC, ln_b + i * DIMC, hn1, hn2);
    k_splitw<<<dim3(DIMC / 32, DFFC / 32), 256, 0, stream>>>(
        W1 + (size_t)i * DIMC * DFFC, DIMC, DFFC, W1t, W1t + (size_t)DFFC * DIMC);
    k_mlp<0><<<dim3(TK / 128, DFFC / 128, 1), 512, 0, stream>>>(
        hn1, hn2, W1t, W1t + (size_t)DFFC * DIMC, pM, DIMC, DIMC,
        b1 + (size_t)i * DFFC, act1, act2, nullptr, DFFC, 1.f / 4096.f);
    k_splitw<<<dim3(DFFC / 32, DIMC / 32), 256, 0, stream>>>(
        W2 + (size_t)i * DFFC * DIMC, DFFC, DIMC, W2t, W2t + (size_t)DIMC * DFFC);
    k_mlp<1><<<dim3(TK / 128, DIMC / 128, 2), 512, 0, stream>>>(
        act1, act2, W2t, W2t + (size_t)DIMC * DFFC, pM, DFFC, DFFC / 2,
        nullptr, nullptr, nullptr, pbuf, DIMC, 1.f / 16384.f);
    k_decide<<<TK, 256, 0, stream>>>(h, pbuf, b2 + (size_t)i * DIMC,
        surv_in, surv_out, pM, cnts, exit_idx, hexit, i);
    k_cvtb<<<2048, 256, 0, stream>>>(Wout, Woutb, VOC * DIMC / 4);
    k_logits<<<dim3(TK / 128, VOC / 128), 512, 0, stream>>>(
        hexit, Woutb, exit_idx, cnts + i, out);
    int* tmp = surv_in; surv_in = surv_out; surv_out = tmp;
  }
}

// Round 4
// 1497.727 us; speedup vs baseline: 3.3397x; 1.1150x over previous
//
#include <hip/hip_runtime.h>
#include <hip/hip_bf16.h>
#include <stdint.h>

constexpr int TK   = 4096;   // B*S tokens
constexpr int DIMC = 1024;
constexpr int DFFC = 4096;
constexpr int VOC  = 32000;
constexpr int NL   = 3;

typedef __attribute__((ext_vector_type(8))) short bf16x8;
typedef __attribute__((ext_vector_type(8))) _Float16 half8;
typedef __attribute__((ext_vector_type(4))) float f32x4;
using u16 = unsigned short;

__device__ __forceinline__ u16 f2bf(float f) {
  unsigned int u = __float_as_uint(f);
  u += 0x7FFF + ((u >> 16) & 1);           // RNE; inputs finite
  return (u16)(u >> 16);
}

__device__ __forceinline__ void split16(float v, u16& hi, u16& lo) {
  _Float16 a = (_Float16)v;
  _Float16 b = (_Float16)(v - (float)a);
  hi = __builtin_bit_cast(u16, a);
  lo = __builtin_bit_cast(u16, b);
}

__device__ __forceinline__ float gelu_f(float x) {
  float x3 = x * x * x;
  return 0.5f * x * (1.0f + tanhf(0.7978845608028654f * (x + 0.044715f * x3)));
}

// async global->LDS, 16B per lane; LDS dest = wave-uniform base + lane*16
__device__ __forceinline__ void gll16(const void* g, void* l) {
  __builtin_amdgcn_global_load_lds(
      (const __attribute__((address_space(1))) unsigned int*)g,
      (__attribute__((address_space(3))) unsigned int*)l, 16, 0, 0);
}

// ---------------- init ----------------
__global__ __launch_bounds__(256) void k_init(const int* __restrict__ x,
    const float* __restrict__ emb, float* __restrict__ h,
    int* __restrict__ surv, int* __restrict__ cnts) {
  const int t = blockIdx.x, tid = threadIdx.x;
  if (t == 0 && tid < 16) cnts[tid] = (tid == 12) ? TK : 0;
  if (tid == 0) surv[t] = t;
  const int tok = x[t];
  ((float4*)(h + (size_t)t * DIMC))[tid] =
      ((const float4*)(emb + (size_t)tok * DIMC))[tid];
}

// ---------------- layernorm -> 2 fp16 planes (x16 scale) ----------------
__global__ __launch_bounds__(256) void k_ln(const float* __restrict__ h,
    const int* __restrict__ surv, const int* __restrict__ pM,
    const float* __restrict__ g, const float* __restrict__ b,
    u16* __restrict__ hn1, u16* __restrict__ hn2) {
  const int bidx = blockIdx.x;
  if (bidx >= *pM) return;
  const int t = surv[bidx];
  const int tid = threadIdx.x;
  const int lane = tid & 63, wid = tid >> 6;
  __shared__ float sm[4];
  float4 v = ((const float4*)(h + (size_t)t * DIMC))[tid];
  float s = v.x + v.y + v.z + v.w;
#pragma unroll
  for (int o = 32; o; o >>= 1) s += __shfl_down(s, o);
  if (lane == 0) sm[wid] = s;
  __syncthreads();
  const float mean = (sm[0] + sm[1] + sm[2] + sm[3]) * (1.0f / DIMC);
  __syncthreads();
  float4 d;
  d.x = v.x - mean; d.y = v.y - mean; d.z = v.z - mean; d.w = v.w - mean;
  float q = d.x * d.x + d.y * d.y + d.z * d.z + d.w * d.w;
#pragma unroll
  for (int o = 32; o; o >>= 1) q += __shfl_down(q, o);
  if (lane == 0) sm[wid] = q;
  __syncthreads();
  const float var = (sm[0] + sm[1] + sm[2] + sm[3]) * (1.0f / DIMC);
  const float rstd = 1.0f / sqrtf(var + 1e-5f);
  float4 gg = ((const float4*)g)[tid];
  float4 bb = ((const float4*)b)[tid];
  float o4[4];
  o4[0] = (d.x * rstd * gg.x + bb.x) * 16.f;
  o4[1] = (d.y * rstd * gg.y + bb.y) * 16.f;
  o4[2] = (d.z * rstd * gg.z + bb.z) * 16.f;
  o4[3] = (d.w * rstd * gg.w + bb.w) * 16.f;
  ushort4 u1, u2;
  split16(o4[0], u1.x, u2.x); split16(o4[1], u1.y, u2.y);
  split16(o4[2], u1.z, u2.z); split16(o4[3], u1.w, u2.w);
  ((ushort4*)(hn1 + (size_t)bidx * DIMC))[tid] = u1;
  ((ushort4*)(hn2 + (size_t)bidx * DIMC))[tid] = u2;
}

// ---------------- weight transpose + fp16 2-split (x256 scale) ----------------
// in W[K][N] f32  ->  O1,O2 [N][K] fp16
__global__ __launch_bounds__(256) void k_splitw(const float* __restrict__ W,
    int K, int N, u16* __restrict__ O1, u16* __restrict__ O2) {
  __shared__ float t[32][33];
  const int bk = blockIdx.x * 32, bn = blockIdx.y * 32;
  const int lx = threadIdx.x & 31, ly = threadIdx.x >> 5;
#pragma unroll
  for (int i = 0; i < 32; i += 8)
    t[ly + i][lx] = W[(size_t)(bk + ly + i) * N + bn + lx];
  __syncthreads();
#pragma unroll
  for (int i = 0; i < 32; i += 8) {
    float v = t[lx][ly + i] * 256.f;
    u16 h1, h2; split16(v, h1, h2);
    const size_t o = (size_t)(bn + ly + i) * K + bk + lx;
    O1[o] = h1; O2[o] = h2;
  }
}

// ---------------- f32 -> bf16 bulk convert (Wout, once per call) ----------------
__global__ __launch_bounds__(256) void k_cvtb(const float* __restrict__ in,
    u16* __restrict__ o, int n4) {
  int i = blockIdx.x * blockDim.x + threadIdx.x;
  const int stride = gridDim.x * blockDim.x;
  for (; i < n4; i += stride) {
    float4 v = ((const float4*)in)[i];
    ushort4 u;
    u.x = f2bf(v.x); u.y = f2bf(v.y); u.z = f2bf(v.z); u.w = f2bf(v.w);
    ((ushort4*)o)[i] = u;
  }
}

// ---------------- fp16 3-term split MFMA GEMM: C ~= (A1+A2)(B1+B2)^T ----------------
// (a2*b2 term dropped: <= 2^-22 relative, below kept-term rounding)
// 4 waves, 64x64 wave tile, 128x128 block, BK=64, global_load_lds staging.
// EPI==0: act = split64(gelu(C*oscale + bias))  -> O1,O2 [TK][N]
// EPI==1: PO[z*TK + m][n] = C*oscale            (split-K partials)
template<int EPI, int LDK>
__global__ __launch_bounds__(256, 2) void k_mlp(
    const u16* __restrict__ A1, const u16* __restrict__ A2,
    const u16* __restrict__ B1, const u16* __restrict__ B2,
    const int* __restrict__ pM, int Kpart,
    const float* __restrict__ bias,
    u16* __restrict__ O1, u16* __restrict__ O2,
    float* __restrict__ PO, int N, float oscale)
{
  const int M = *pM;
  const int rb = blockIdx.x;
  if (rb * 128 >= M) return;
  const int n0 = blockIdx.y * 128;
  const int kz = blockIdx.z * Kpart;

  __shared__ u16 S[4][128 * 64];   // A1,A2,B1,B2 tiles; 64 KiB
  const int tid = threadIdx.x;
  const int w = tid >> 6, l = tid & 63;

  // staging: linear LDS dest, inverse-swizzled global source (rule 21)
  const int sr = l >> 3;                       // row within 8-row chunk (== row&7)
  const int sc = ((l & 7) ^ sr) * 8;           // swizzled source k-chunk (elems)
  const u16* gp[4];
  {
    const u16* gsrc[4] = {A1, A2, B1, B2};
#pragma unroll
    for (int p = 0; p < 4; ++p) {
      const int row0 = (p < 2) ? rb * 128 : n0;
      gp[p] = gsrc[p] + (size_t)(row0 + w * 32 + sr) * LDK + kz + sc;
    }
  }

  // compute: 2x2 wave grid, wave tile 64x64
  const int wr = w >> 1, wc = w & 1;
  const int lr = l & 15, hi = l >> 4;
  const int sw = lr & 7;
  const int swz0 = (hi ^ sw) * 8;              // ks=0 chunk swizzle (elems)
  const int swz1 = ((4 + hi) ^ sw) * 8;        // ks=1
  const int abase = (wr * 64 + lr) * 64;
  const int bbase = (wc * 64 + lr) * 64;

  f32x4 acc[4][4];
#pragma unroll
  for (int mi = 0; mi < 4; ++mi)
#pragma unroll
    for (int ni = 0; ni < 4; ++ni) acc[mi][ni] = (f32x4){0.f, 0.f, 0.f, 0.f};

  const int NT = Kpart / 64;
  for (int kt = 0; kt < NT; ++kt) {
    __syncthreads();               // prior reads of S complete
#pragma unroll
    for (int p = 0; p < 4; ++p)
#pragma unroll
      for (int j = 0; j < 4; ++j)
        gll16(gp[p] + (size_t)j * 8 * LDK + kt * 64,
              (void*)&S[p][(w * 32 + j * 8) * 64]);
    __syncthreads();               // compiler drains vmcnt(0) before barrier
#pragma unroll
    for (int ks = 0; ks < 2; ++ks) {
      const int kswz = ks ? swz1 : swz0;
      half8 a1[4], a2[4], b1v[4], b2v[4];
#pragma unroll
      for (int mi = 0; mi < 4; ++mi) {
        a1[mi] = *(const half8*)&S[0][abase + mi * 1024 + kswz];
        a2[mi] = *(const half8*)&S[1][abase + mi * 1024 + kswz];
      }
#pragma unroll
      for (int ni = 0; ni < 4; ++ni) {
        b1v[ni] = *(const half8*)&S[2][bbase + ni * 1024 + kswz];
        b2v[ni] = *(const half8*)&S[3][bbase + ni * 1024 + kswz];
      }
#pragma unroll
      for (int mi = 0; mi < 4; ++mi)
#pragma unroll
        for (int ni = 0; ni < 4; ++ni) {
          acc[mi][ni] = __builtin_amdgcn_mfma_f32_16x16x32_f16(a2[mi], b1v[ni], acc[mi][ni], 0, 0, 0);
          acc[mi][ni] = __builtin_amdgcn_mfma_f32_16x16x32_f16(a1[mi], b2v[ni], acc[mi][ni], 0, 0, 0);
          acc[mi][ni] = __builtin_amdgcn_mfma_f32_16x16x32_f16(a1[mi], b1v[ni], acc[mi][ni], 0, 0, 0);
        }
    }
  }

#pragma unroll
  for (int mi = 0; mi < 4; ++mi)
#pragma unroll
    for (int ni = 0; ni < 4; ++ni) {
      const int n = n0 + wc * 64 + ni * 16 + lr;
#pragma unroll
      for (int r = 0; r < 4; ++r) {
        const int m = rb * 128 + wr * 64 + mi * 16 + hi * 4 + r;
        float v = acc[mi][ni][r] * oscale;
        if constexpr (EPI == 0) {
          v = gelu_f(v + bias[n]) * 64.f;
          u16 h1, h2; split16(v, h1, h2);
          O1[(size_t)m * N + n] = h1;
          O2[(size_t)m * N + n] = h2;
        } else {
          PO[(size_t)(blockIdx.z * TK + m) * N + n] = v;
        }
      }
    }
}

// ---------------- decide: o = h + p0 + p1 + b2; cos; route token ----------------
__global__ __launch_bounds__(256) void k_decide(
    float* __restrict__ h, const float* __restrict__ p,
    const float* __restrict__ bias,
    const int* __restrict__ surv_in, int* __restrict__ surv_out,
    const int* __restrict__ pM, int* __restrict__ cnts,
    int* __restrict__ exit_idx, u16* __restrict__ hexit,
    int stage)
{
  const int bidx = blockIdx.x;
  if (bidx >= *pM) return;
  const int t = surv_in[bidx];
  const int tid = threadIdx.x;
  const int lane = tid & 63, wid = tid >> 6;
  __shared__ float sm[12];
  __shared__ int sif[2];
  float4 a  = ((const float4*)(h + (size_t)t * DIMC))[tid];
  float4 p0 = ((const float4*)(p + (size_t)bidx * DIMC))[tid];
  float4 p1 = ((const float4*)(p + (size_t)(TK + bidx) * DIMC))[tid];
  float4 bb = ((const float4*)bias)[tid];
  float4 o;
  o.x = a.x + p0.x + p1.x + bb.x;
  o.y = a.y + p0.y + p1.y + bb.y;
  o.z = a.z + p0.z + p1.z + bb.z;
  o.w = a.w + p0.w + p1.w + bb.w;
  float hh = a.x * a.x + a.y * a.y + a.z * a.z + a.w * a.w;
  float ho = a.x * o.x + a.y * o.y + a.z * o.z + a.w * o.w;
  float oo = o.x * o.x + o.y * o.y + o.z * o.z + o.w * o.w;
#pragma unroll
  for (int off = 32; off; off >>= 1) {
    hh += __shfl_down(hh, off);
    ho += __shfl_down(ho, off);
    oo += __shfl_down(oo, off);
  }
  if (lane == 0) { sm[wid] = hh; sm[4 + wid] = ho; sm[8 + wid] = oo; }
  __syncthreads();
  if (tid == 0) {
    int take;
    if (stage == NL - 1) take = 1;
    else {
      const float HH = sm[0] + sm[1] + sm[2] + sm[3];
      const float HO = sm[4] + sm[5] + sm[6] + sm[7];
      const float OO = sm[8] + sm[9] + sm[10] + sm[11];
      const float cosv = HO / (sqrtf(HH) * sqrtf(OO) + 1e-8f);
      take = (cosv >= 0.98f) ? 1 : 0;
    }
    int pos;
    if (take) {
      pos = atomicAdd(&cnts[stage], 1);
      exit_idx[pos] = t;
    } else {
      pos = atomicAdd(&cnts[4 + stage], 1);
      surv_out[pos] = t;
    }
    sif[0] = take; sif[1] = pos;
  }
  __syncthreads();
  if (sif[0]) {
    u16* dst = hexit + (size_t)sif[1] * DIMC;
    ushort4 u;
    u.x = f2bf(o.x); u.y = f2bf(o.y); u.z = f2bf(o.z); u.w = f2bf(o.w);
    ((ushort4*)dst)[tid] = u;
  } else {
    ((float4*)(h + (size_t)t * DIMC))[tid] = o;
  }
}

// ---------------- logits: bf16 MFMA GEMM, 4 waves, 64x64 wave tile ----------------
__global__ __launch_bounds__(256, 2) void k_logits(
    const u16* __restrict__ Ab,        // hexit [TK][DIMC] bf16
    const u16* __restrict__ Wb,        // Woutb [VOC][DIMC] bf16
    const int* __restrict__ exit_idx,
    const int* __restrict__ pcnt,
    float* __restrict__ out)
{
  const int cnt = *pcnt;
  const int rb = blockIdx.x;
  if (rb * 128 >= cnt) return;
  const int cb = blockIdx.y;

  __shared__ u16 S[2][128 * 64];       // 32 KiB
  const int tid = threadIdx.x;
  const int w = tid >> 6, l = tid & 63;

  const int sr = l >> 3;
  const int sc = ((l & 7) ^ sr) * 8;
  const u16* gp[2];
  gp[0] = Ab + (size_t)(rb * 128 + w * 32 + sr) * DIMC + sc;
  gp[1] = Wb + (size_t)(cb * 128 + w * 32 + sr) * DIMC + sc;

  const int wr = w >> 1, wc = w & 1;
  const int lr = l & 15, hi = l >> 4;
  const int sw = lr & 7;
  const int swz0 = (hi ^ sw) * 8;
  const int swz1 = ((4 + hi) ^ sw) * 8;
  const int abase = (wr * 64 + lr) * 64;
  const int bbase = (wc * 64 + lr) * 64;

  f32x4 acc[4][4];
#pragma unroll
  for (int mi = 0; mi < 4; ++mi)
#pragma unroll
    for (int ni = 0; ni < 4; ++ni) acc[mi][ni] = (f32x4){0.f, 0.f, 0.f, 0.f};

  const int NT = DIMC / 64;            // 16
  for (int kt = 0; kt < NT; ++kt) {
    __syncthreads();
#pragma unroll
    for (int p = 0; p < 2; ++p)
#pragma unroll
      for (int j = 0; j < 4; ++j)
        gll16(gp[p] + (size_t)j * 8 * DIMC + kt * 64,
              (void*)&S[p][(w * 32 + j * 8) * 64]);
    __syncthreads();
#pragma unroll
    for (int ks = 0; ks < 2; ++ks) {
      const int kswz = ks ? swz1 : swz0;
      bf16x8 aF[4], bF[4];
#pragma unroll
      for (int mi = 0; mi < 4; ++mi)
        aF[mi] = *(const bf16x8*)&S[0][abase + mi * 1024 + kswz];
#pragma unroll
      for (int ni = 0; ni < 4; ++ni)
        bF[ni] = *(const bf16x8*)&S[1][bbase + ni * 1024 + kswz];
#pragma unroll
      for (int mi = 0; mi < 4; ++mi)
#pragma unroll
        for (int ni = 0; ni < 4; ++ni)
          acc[mi][ni] = __builtin_amdgcn_mfma_f32_16x16x32_bf16(aF[mi], bF[ni], acc[mi][ni], 0, 0, 0);
    }
  }

  const int mvalid = cnt - rb * 128;
#pragma unroll
  for (int mi = 0; mi < 4; ++mi)
#pragma unroll
    for (int r = 0; r < 4; ++r) {
      const int mrow = wr * 64 + mi * 16 + hi * 4 + r;
      if (mrow < mvalid) {
        const int tok = exit_idx[rb * 128 + mrow];
        float* orow = out + (size_t)tok * VOC + cb * 128 + wc * 64 + lr;
#pragma unroll
        for (int ni = 0; ni < 4; ++ni)
          orow[ni * 16] = acc[mi][ni][r];
      }
    }
}

// ---------------- host ----------------
extern "C" void kernel_launch(void* const* d_in, const int* in_sizes, int n_in,
                              void* d_out, int out_size, void* d_ws, size_t ws_size,
                              hipStream_t stream)
{
  const int*   x    = (const int*)d_in[0];
  const float* emb  = (const float*)d_in[1];
  const float* ln_g = (const float*)d_in[2];
  const float* ln_b = (const float*)d_in[3];
  const float* W1   = (const float*)d_in[4];
  const float* b1   = (const float*)d_in[5];
  const float* W2   = (const float*)d_in[6];
  const float* b2   = (const float*)d_in[7];
  const float* Wout = (const float*)d_in[8];
  float* out = (float*)d_out;

  char* p = (char*)d_ws;
  size_t off = 0;
  auto alloc = [&](size_t bytes) -> void* {
    void* r = p + off;
    off += (bytes + 255) & ~(size_t)255;
    return r;
  };
  float* h    = (float*)alloc((size_t)TK * DIMC * 4);
  float* pbuf = (float*)alloc((size_t)2 * TK * DIMC * 4);   // gemm2 partials; hn planes alias
  u16* hn1 = (u16*)pbuf;
  u16* hn2 = hn1 + (size_t)TK * DIMC;
  u16* act1 = (u16*)alloc((size_t)TK * DFFC * 2);
  u16* act2 = (u16*)alloc((size_t)TK * DFFC * 2);
  u16* Woutb = (u16*)alloc((size_t)VOC * DIMC * 2);         // dedicated; converted once
  u16* W1t = (u16*)alloc((size_t)2 * DFFC * DIMC * 2);
  u16* W2t = (u16*)alloc((size_t)2 * DIMC * DFFC * 2);
  u16* hexit = (u16*)alloc((size_t)TK * DIMC * 2);
  int* exit_idx = (int*)alloc((size_t)TK * 4);
  int* surv_a   = (int*)alloc((size_t)TK * 4);
  int* surv_b   = (int*)alloc((size_t)TK * 4);
  int* cnts     = (int*)alloc(64 * 4);
  // cnts[0..2]=exit counts; cnts[4..6]=survivor counts; cnts[12]=TK

  k_init<<<TK, 256, 0, stream>>>(x, emb, h, surv_a, cnts);
  k_cvtb<<<2048, 256, 0, stream>>>(Wout, Woutb, VOC * DIMC / 4);
  int* surv_in  = surv_a;
  int* surv_out = surv_b;
  for (int i = 0; i < NL; ++i) {
    const int* pM = (i == 0) ? (cnts + 12) : (cnts + 4 + (i - 1));
    k_ln<<<TK, 256, 0, stream>>>(h, surv_in, pM, ln_g + i * DIMC, ln_b + i * DIMC, hn1, hn2);
    k_splitw<<<dim3(DIMC / 32, DFFC / 32), 256, 0, stream>>>(
        W1 + (size_t)i * DIMC * DFFC, DIMC, DFFC, W1t, W1t + (size_t)DFFC * DIMC);
    k_mlp<0, DIMC><<<dim3(TK / 128, DFFC / 128, 1), 256, 0, stream>>>(
        hn1, hn2, W1t, W1t + (size_t)DFFC * DIMC, pM, DIMC,
        b1 + (size_t)i * DFFC, act1, act2, nullptr, DFFC, 1.f / 4096.f);
    k_splitw<<<dim3(DFFC / 32, DIMC / 32), 256, 0, stream>>>(
        W2 + (size_t)i * DFFC * DIMC, DFFC, DIMC, W2t, W2t + (size_t)DIMC * DFFC);
    k_mlp<1, DFFC><<<dim3(TK / 128, DIMC / 128, 2), 256, 0, stream>>>(
        act1, act2, W2t, W2t + (size_t)DIMC * DFFC, pM, DFFC / 2,
        nullptr, nullptr, nullptr, pbuf, DIMC, 1.f / 16384.f);
    k_decide<<<TK, 256, 0, stream>>>(h, pbuf, b2 + (size_t)i * DIMC,
        surv_in, surv_out, pM, cnts, exit_idx, hexit, i);
    k_logits<<<dim3(TK / 128, VOC / 128), 256, 0, stream>>>(
        hexit, Woutb, exit_idx, cnts + i, out);
    int* tmp = surv_in; surv_in = surv_out; surv_out = tmp;
  }
}